// Round 3
// 988.635 us; speedup vs baseline: 1.0072x; 1.0072x over previous
//
#include <hip/hip_runtime.h>

#define NEXP 8
#define HID 2048
#define INTER 4096
#define NTOK 1024
#define CAP 512     // per-expert row capacity (mean load = 256, 512 is +17 sigma)
#define BK 64

// compiler memory fence (IR level) + scheduler fence (MIR level).
// Raw s_barrier is IntrNoMem -- it does NOT fence memory ops; every barrier
// crossing in the pipelined schedule must be bracketed by FENCE().
#define FENCE() do { asm volatile("" ::: "memory"); __builtin_amdgcn_sched_barrier(0); } while (0)

typedef short bf8 __attribute__((ext_vector_type(8)));   // 8 bf16 = 4 VGPRs
typedef float f4  __attribute__((ext_vector_type(4)));

__device__ __forceinline__ unsigned short f2bf(float f) {
  unsigned u = __builtin_bit_cast(unsigned, f);
  u += 0x7fffu + ((u >> 16) & 1u);      // RNE (inputs are finite; no NaN handling needed)
  return (unsigned short)(u >> 16);
}

__device__ __forceinline__ void ld_lds16(const void* g, void* l) {
  // async global->LDS, 16B/lane; LDS dest = wave-uniform base + lane*16
  __builtin_amdgcn_global_load_lds(
      (const __attribute__((address_space(1))) unsigned*)g,
      (__attribute__((address_space(3))) unsigned*)l, 16, 0, 0);
}

__device__ __forceinline__ void packB8(unsigned short* dst, float4 a, float4 b) {
  union { bf8 v; unsigned short u[8]; } p;
  p.u[0] = f2bf(a.x); p.u[1] = f2bf(a.y); p.u[2] = f2bf(a.z); p.u[3] = f2bf(a.w);
  p.u[4] = f2bf(b.x); p.u[5] = f2bf(b.y); p.u[6] = f2bf(b.z); p.u[7] = f2bf(b.w);
  *(bf8*)dst = p.v;   // 16B-aligned (row stride 128B, chunk*16B)
}

// ---------------- router: softmax -> top2 -> renormalize -> compact per expert
__global__ void k_router(const float* __restrict__ lg, int* __restrict__ cnt,
                         int* __restrict__ tok, float* __restrict__ wgt) {
  __shared__ int lc[NEXP];
  int t = threadIdx.x;
  if (t < NEXP) lc[t] = 0;
  __syncthreads();
  float l[NEXP];
#pragma unroll
  for (int i = 0; i < NEXP; ++i) l[i] = lg[t * NEXP + i];
  int i1 = 0; float v1 = l[0];
#pragma unroll
  for (int i = 1; i < NEXP; ++i) if (l[i] > v1) { v1 = l[i]; i1 = i; }
  int i2 = -1; float v2 = -3.4e38f;
#pragma unroll
  for (int i = 0; i < NEXP; ++i) if (i != i1 && l[i] > v2) { v2 = l[i]; i2 = i; }
  // renormalized top-2 softmax: full-softmax denominator cancels
  float e2 = __expf(v2 - v1);
  float w1 = 1.f / (1.f + e2);
  float w2 = e2 / (1.f + e2);
  int s1 = atomicAdd(&lc[i1], 1);
  if (s1 < CAP) { tok[i1 * CAP + s1] = t; wgt[i1 * CAP + s1] = w1; }
  int s2 = atomicAdd(&lc[i2], 1);
  if (s2 < CAP) { tok[i2 * CAP + s2] = t; wgt[i2 * CAP + s2] = w2; }
  __syncthreads();
  if (t < NEXP) cnt[t] = lc[t];
}

// ---------------- gather: pack routed tokens into dense bf16 rows per expert
__global__ void k_gather(const float* __restrict__ hid, const int* __restrict__ cnt,
                         const int* __restrict__ tok, unsigned short* __restrict__ hs) {
  int b = blockIdx.x;
  int e = b >> 9, s = b & (CAP - 1);
  if (s >= cnt[e]) return;
  int t = tok[e * CAP + s];
  const float4* src = (const float4*)(hid + (size_t)t * HID);
  ushort4* dst = (ushort4*)(hs + ((size_t)e * CAP + s) * HID);
  for (int i = threadIdx.x; i < HID / 4; i += 128) {
    float4 v = src[i];
    ushort4 o = make_ushort4(f2bf(v.x), f2bf(v.y), f2bf(v.z), f2bf(v.w));
    dst[i] = o;
  }
}

// ---------------- GEMM1 (+fused SwiGLU): act[e,row,0:4096] from hsort @ W13[e]^T
// 2-phase pipelined schedule: B(k+1) prefetched to regs one K-step ahead ->
// packed into double-buffered lB; A(k+1) staged via global_load_lds after the
// post-MFMA barrier; pre-MFMA barrier waits counted vmcnt(4) so the next B
// prefetch stays in flight across the barrier. VMEM issue order is pinned by
// FENCE() so the 4 youngest outstanding ops at the wait are provably the B
// prefetch loads (the round-2 race was this invariant being unpinned).
__global__ __launch_bounds__(256, 2) void k_gemm1(
    const unsigned short* __restrict__ hs, const float* __restrict__ W13,
    const int* __restrict__ cnt, unsigned short* __restrict__ act) {
  int e = blockIdx.x >> 7;
  int n0 = (blockIdx.x & 127) * 32;
  int count = cnt[e];
  if (count <= 0) return;
  if (count > CAP) count = CAP;

  __shared__ __align__(16) unsigned short lA[3 * 128 * BK];   // 48 KB (single buf)
  __shared__ __align__(16) unsigned short lB[2][64 * BK];     // 2 x 8 KB (dbuf)

  int tid = threadIdx.x;
  int wv = tid >> 6, ln = tid & 63;
  int quad = ln >> 4, l16 = ln & 15;

  const unsigned short* A0 = hs + (size_t)e * CAP * HID;
  const float* B = W13 + (size_t)e * (2 * INTER) * HID;

  // B staging geometry: 64 rows x 8 chunks, XOR chunk swizzle
  int r0 = tid >> 3;          // 0..31 (gate), r0+32 = up
  int bc = tid & 7;
  const float* g0 = B + (size_t)(n0 + r0) * HID + bc * 8;
  const float* g1 = B + (size_t)(INTER + n0 + r0) * HID + bc * 8;
  int wpo0 = r0 * BK + ((bc ^ (r0 & 7)) * 8);
  int wpo1 = (r0 + 32) * BK + ((bc ^ (r0 & 7)) * 8);

  for (int m0 = 0; m0 < count; m0 += 384) {
    int rem = count - m0;
    int mtLive = (rem + 127) >> 7; if (mtLive > 3) mtLive = 3;
    int nIss = mtLive * 4;
    const unsigned short* A = A0 + (size_t)m0 * HID;

    f4 acc[3][2][2][2];   // [mt][msub][mat(g/u)][nsub]
#pragma unroll
    for (int a = 0; a < 3; ++a)
#pragma unroll
      for (int b2 = 0; b2 < 2; ++b2)
#pragma unroll
        for (int c = 0; c < 2; ++c)
#pragma unroll
          for (int d = 0; d < 2; ++d) acc[a][b2][c][d] = (f4){0.f, 0.f, 0.f, 0.f};

    // ---- prologue. VMEM age order (oldest->youngest): B(0) regs, A(0) lds,
    // B(1) regs. Then vmcnt(4) drains A(0) while B(1) stays in flight.
    float4 c0 = *(const float4*)(g0 + 0);
    float4 c1 = *(const float4*)(g0 + 4);
    float4 c2 = *(const float4*)(g1 + 0);
    float4 c3 = *(const float4*)(g1 + 4);
    FENCE();
    for (int j = 0; j < nIss; ++j) {
      int rl = j * 32 + (tid >> 3);
      int cg = (tid & 7) ^ (rl & 7);
      ld_lds16(A + (size_t)rl * HID + cg * 8, &lA[j * 2048 + wv * 512]);
    }
    FENCE();
    packB8(&lB[0][wpo0], c0, c1);
    packB8(&lB[0][wpo1], c2, c3);
    c0 = *(const float4*)(g0 + BK);
    c1 = *(const float4*)(g0 + BK + 4);
    c2 = *(const float4*)(g1 + BK);
    c3 = *(const float4*)(g1 + BK + 4);
    FENCE();
    asm volatile("s_waitcnt vmcnt(4) lgkmcnt(0)" ::: "memory");
    __builtin_amdgcn_sched_barrier(0);
    __builtin_amdgcn_s_barrier();
    FENCE();

    int kb = 0;
    for (int k0 = 0; k0 < HID; k0 += BK, kb ^= 1) {
      const unsigned short* lBk = lB[kb];
      __builtin_amdgcn_s_setprio(1);
#pragma unroll
      for (int ks = 0; ks < 2; ++ks) {
        int c = ks * 4 + quad;
        bf8 bg[2][2];
#pragma unroll
        for (int mat = 0; mat < 2; ++mat)
#pragma unroll
          for (int ns = 0; ns < 2; ++ns) {
            int br = mat * 32 + ns * 16 + l16;
            bg[mat][ns] = *(const bf8*)&lBk[br * BK + ((c ^ (br & 7)) * 8)];
          }
#pragma unroll
        for (int mt = 0; mt < 3; ++mt) {
          if (mt >= mtLive) break;
#pragma unroll
          for (int ms = 0; ms < 2; ++ms) {
            int rl = mt * 128 + wv * 32 + ms * 16 + l16;
            bf8 a = *(const bf8*)&lA[rl * BK + ((c ^ (rl & 7)) * 8)];
#pragma unroll
            for (int mat = 0; mat < 2; ++mat)
#pragma unroll
              for (int ns = 0; ns < 2; ++ns)
                acc[mt][ms][mat][ns] = __builtin_amdgcn_mfma_f32_16x16x32_bf16(
                    a, bg[mat][ns], acc[mt][ms][mat][ns], 0, 0, 0);
          }
        }
      }
      __builtin_amdgcn_s_setprio(0);
      FENCE();
      __builtin_amdgcn_s_barrier();            // all lA/lB[kb] reads complete
      FENCE();
      if (k0 + BK < HID) {
        // pack B(k+1) from regs prefetched a full K-step ago -> lB[kb^1]
        packB8(&lB[kb ^ 1][wpo0], c0, c1);
        packB8(&lB[kb ^ 1][wpo1], c2, c3);
        // stage A(k+1) into lA (pinned strictly before the counted B loads)
        for (int j = 0; j < nIss; ++j) {
          int rl = j * 32 + (tid >> 3);
          int cg = (tid & 7) ^ (rl & 7);
          ld_lds16(A + (size_t)rl * HID + (k0 + BK) + cg * 8, &lA[j * 2048 + wv * 512]);
        }
        FENCE();
        // prefetch B(k+2) regs (wrap on tail keeps vmcnt count uniform)
        int kn = (k0 + 2 * BK < HID) ? (k0 + 2 * BK) : 0;
        c0 = *(const float4*)(g0 + kn);
        c1 = *(const float4*)(g0 + kn + 4);
        c2 = *(const float4*)(g1 + kn);
        c3 = *(const float4*)(g1 + kn + 4);
        FENCE();
        // A(k+1) landed in LDS; B(k+2) regs stay in flight across the barrier
        asm volatile("s_waitcnt vmcnt(4) lgkmcnt(0)" ::: "memory");
        __builtin_amdgcn_sched_barrier(0);
        __builtin_amdgcn_s_barrier();
        FENCE();
      }
    }

    // epilogue: SwiGLU, store bf16 act. C/D layout: col=lane&15, row=quad*4+reg
    size_t actE = (size_t)e * CAP * INTER;
#pragma unroll
    for (int mt = 0; mt < 3; ++mt) {
      if (mt >= mtLive) break;
#pragma unroll
      for (int ms = 0; ms < 2; ++ms) {
        int rbase = m0 + mt * 128 + wv * 32 + ms * 16 + quad * 4;
#pragma unroll
        for (int ns = 0; ns < 2; ++ns) {
          int col = n0 + ns * 16 + l16;
#pragma unroll
          for (int r = 0; r < 4; ++r) {
            int row = rbase + r;
            if (row < count) {
              float g = acc[mt][ms][0][ns][r];
              float u = acc[mt][ms][1][ns][r];
              float sv = g / (1.f + __expf(-g)) * u;
              act[actE + (size_t)row * INTER + col] = f2bf(sv);
            }
          }
        }
      }
    }
  }
}

// ---------------- GEMM2: out[t,:] += w * (act[e] @ W2[e]^T), scatter via atomics
// Same 2-phase pipelined schedule as GEMM1 (counted vmcnt(2) for the B prefetch).
__global__ __launch_bounds__(256, 2) void k_gemm2(
    const unsigned short* __restrict__ act, const float* __restrict__ W2,
    const int* __restrict__ cnt, const int* __restrict__ tok,
    const float* __restrict__ wgt, float* __restrict__ out) {
  int e = blockIdx.x >> 6;
  int n0 = (blockIdx.x & 63) * 32;
  int count = cnt[e];
  if (count <= 0) return;
  if (count > CAP) count = CAP;

  __shared__ __align__(16) unsigned short lA[3 * 128 * BK];   // 48 KB (single buf)
  __shared__ __align__(16) unsigned short lB[2][32 * BK];     // 2 x 4 KB (dbuf)

  int tid = threadIdx.x;
  int wv = tid >> 6, ln = tid & 63;
  int quad = ln >> 4, l16 = ln & 15;

  const unsigned short* A0 = act + (size_t)e * CAP * INTER;
  const float* B = W2 + (size_t)e * HID * INTER;

  int r0 = tid >> 3;   // 0..31
  int bc = tid & 7;
  const float* g0 = B + (size_t)(n0 + r0) * INTER + bc * 8;
  int wpo0 = r0 * BK + ((bc ^ (r0 & 7)) * 8);

  for (int m0 = 0; m0 < count; m0 += 384) {
    int rem = count - m0;
    int mtLive = (rem + 127) >> 7; if (mtLive > 3) mtLive = 3;
    int nIss = mtLive * 4;
    const unsigned short* A = A0 + (size_t)m0 * INTER;

    f4 acc[3][2][2];   // [mt][msub][nsub]
#pragma unroll
    for (int a = 0; a < 3; ++a)
#pragma unroll
      for (int b2 = 0; b2 < 2; ++b2)
#pragma unroll
        for (int c = 0; c < 2; ++c) acc[a][b2][c] = (f4){0.f, 0.f, 0.f, 0.f};

    // ---- prologue (same pinned age order as GEMM1)
    float4 c0 = *(const float4*)(g0 + 0);
    float4 c1 = *(const float4*)(g0 + 4);
    FENCE();
    for (int j = 0; j < nIss; ++j) {
      int rl = j * 32 + (tid >> 3);
      int cg = (tid & 7) ^ (rl & 7);
      ld_lds16(A + (size_t)rl * INTER + cg * 8, &lA[j * 2048 + wv * 512]);
    }
    FENCE();
    packB8(&lB[0][wpo0], c0, c1);
    c0 = *(const float4*)(g0 + BK);
    c1 = *(const float4*)(g0 + BK + 4);
    FENCE();
    asm volatile("s_waitcnt vmcnt(2) lgkmcnt(0)" ::: "memory");
    __builtin_amdgcn_sched_barrier(0);
    __builtin_amdgcn_s_barrier();
    FENCE();

    int kb = 0;
    for (int k0 = 0; k0 < INTER; k0 += BK, kb ^= 1) {
      const unsigned short* lBk = lB[kb];
      __builtin_amdgcn_s_setprio(1);
#pragma unroll
      for (int ks = 0; ks < 2; ++ks) {
        int c = ks * 4 + quad;
        bf8 bb[2];
#pragma unroll
        for (int ns = 0; ns < 2; ++ns) {
          int br = ns * 16 + l16;
          bb[ns] = *(const bf8*)&lBk[br * BK + ((c ^ (br & 7)) * 8)];
        }
#pragma unroll
        for (int mt = 0; mt < 3; ++mt) {
          if (mt >= mtLive) break;
#pragma unroll
          for (int ms = 0; ms < 2; ++ms) {
            int rl = mt * 128 + wv * 32 + ms * 16 + l16;
            bf8 a = *(const bf8*)&lA[rl * BK + ((c ^ (rl & 7)) * 8)];
#pragma unroll
            for (int ns = 0; ns < 2; ++ns)
              acc[mt][ms][ns] = __builtin_amdgcn_mfma_f32_16x16x32_bf16(
                  a, bb[ns], acc[mt][ms][ns], 0, 0, 0);
          }
        }
      }
      __builtin_amdgcn_s_setprio(0);
      FENCE();
      __builtin_amdgcn_s_barrier();            // all lA/lB[kb] reads complete
      FENCE();
      if (k0 + BK < INTER) {
        packB8(&lB[kb ^ 1][wpo0], c0, c1);
        for (int j = 0; j < nIss; ++j) {
          int rl = j * 32 + (tid >> 3);
          int cg = (tid & 7) ^ (rl & 7);
          ld_lds16(A + (size_t)rl * INTER + (k0 + BK) + cg * 8, &lA[j * 2048 + wv * 512]);
        }
        FENCE();
        int kn = (k0 + 2 * BK < INTER) ? (k0 + 2 * BK) : 0;
        c0 = *(const float4*)(g0 + kn);
        c1 = *(const float4*)(g0 + kn + 4);
        FENCE();
        asm volatile("s_waitcnt vmcnt(2) lgkmcnt(0)" ::: "memory");
        __builtin_amdgcn_sched_barrier(0);
        __builtin_amdgcn_s_barrier();
        FENCE();
      }
    }

    // epilogue: weighted scatter-add into out
#pragma unroll
    for (int mt = 0; mt < 3; ++mt) {
      if (mt >= mtLive) break;
#pragma unroll
      for (int ms = 0; ms < 2; ++ms) {
        int rbase = m0 + mt * 128 + wv * 32 + ms * 16 + quad * 4;
#pragma unroll
        for (int ns = 0; ns < 2; ++ns) {
          int col = n0 + ns * 16 + l16;
#pragma unroll
          for (int r = 0; r < 4; ++r) {
            int row = rbase + r;
            if (row < count) {
              int t = tok[e * CAP + row];
              float w = wgt[e * CAP + row];
              atomicAdd(out + (size_t)t * HID + col, w * acc[mt][ms][ns][r]);
            }
          }
        }
      }
    }
  }
}

extern "C" void kernel_launch(void* const* d_in, const int* in_sizes, int n_in,
                              void* d_out, int out_size, void* d_ws, size_t ws_size,
                              hipStream_t stream) {
  const float* hidden = (const float*)d_in[0];
  const float* logits = (const float*)d_in[1];
  const float* W13    = (const float*)d_in[2];
  const float* W2     = (const float*)d_in[3];
  // d_in[4] = top_k (fixed at 2 in the reference module)
  float* out = (float*)d_out;

  // workspace layout (~48.1 MB total)
  char* wsb = (char*)d_ws;
  int*   cnt = (int*)wsb;                                   // 8 ints (256 B reserved)
  int*   tok = (int*)(wsb + 256);                           // 8*512 int  (16 KB)
  float* wgt = (float*)(wsb + 256 + NEXP * CAP * 4);        // 8*512 f32  (16 KB)
  unsigned short* hs  = (unsigned short*)(wsb + 256 + NEXP * CAP * 8);  // 16 MB bf16
  unsigned short* actb = hs + (size_t)NEXP * CAP * HID;                 // 32 MB bf16

  hipMemsetAsync(d_out, 0, (size_t)out_size * sizeof(float), stream);
  k_router<<<1, 1024, 0, stream>>>(logits, cnt, tok, wgt);
  k_gather<<<NEXP * CAP, 128, 0, stream>>>(hidden, cnt, tok, hs);
  k_gemm1<<<NEXP * 128, 256, 0, stream>>>(hs, W13, cnt, actb);
  k_gemm2<<<NEXP * 64, 256, 0, stream>>>(actb, W2, cnt, tok, wgt, out);
}